// Round 1
// baseline (109.085 us; speedup 1.0000x reference)
//
#include <hip/hip_runtime.h>
#include <math.h>

#define NPTS 4096
#define BLK 256
#define BLOCKS_PER_UNIT (NPTS / BLK)   // 16
#define NUNITS 16                      // 8 batches * 2 directions
#define TOTAL_BLOCKS (NUNITS * BLOCKS_PER_UNIT)  // 256
#define CNT 12288.0f                   // N*D elements per std

// ---------------------------------------------------------------------------
// Kernel 1: per-block partial (sum, sumsq) of NN residuals.
// Block -> (unit, query-chunk). unit = 2*batch + dir.
//   dir 0: residuals of x[b] vs NN in y[b]
//   dir 1: residuals of y[b] vs NN in x[b]
// Deterministic: each block writes its own float2 partial (no atomics).
// ---------------------------------------------------------------------------
__global__ __launch_bounds__(BLK) void nn_partial_kernel(
    const float* __restrict__ x, const float* __restrict__ y,
    float2* __restrict__ partials) {
  __shared__ float tx[NPTS];   // 16 KB
  __shared__ float ty[NPTS];   // 16 KB
  __shared__ float tz[NPTS];   // 16 KB
  __shared__ float wS[4], wSS[4];

  const int unit = blockIdx.x >> 4;    // 0..15
  const int blk  = blockIdx.x & 15;    // query chunk within unit
  const int b    = unit >> 1;
  const int dir  = unit & 1;
  const float* __restrict__ Aptr = (dir == 0 ? x : y) + (size_t)b * NPTS * 3;
  const float* __restrict__ Bptr = (dir == 0 ? y : x) + (size_t)b * NPTS * 3;

  // Stage target cloud into LDS (SoA for broadcast-friendly reads).
  for (int i = threadIdx.x; i < NPTS; i += BLK) {
    tx[i] = Bptr[3 * i + 0];
    ty[i] = Bptr[3 * i + 1];
    tz[i] = Bptr[3 * i + 2];
  }
  __syncthreads();

  // One query point per thread.
  const int q = blk * BLK + (int)threadIdx.x;
  const float qx = Aptr[3 * q + 0];
  const float qy = Aptr[3 * q + 1];
  const float qz = Aptr[3 * q + 2];

  float best = 3.4e38f;
  int bi = 0;
  #pragma unroll 8
  for (int j = 0; j < NPTS; ++j) {
    const float dx = qx - tx[j];
    const float dy = qy - ty[j];
    const float dz = qz - tz[j];
    const float d2 = fmaf(dx, dx, fmaf(dy, dy, dz * dz));
    // strict < keeps the FIRST minimal index (matches argmin tie-break)
    if (d2 < best) { best = d2; bi = j; }
  }

  const float rx = qx - tx[bi];
  const float ry = qy - ty[bi];
  const float rz = qz - tz[bi];
  float s  = rx + ry + rz;
  float ss = fmaf(rx, rx, fmaf(ry, ry, rz * rz));

  // wave64 shuffle reduction
  #pragma unroll
  for (int off = 32; off > 0; off >>= 1) {
    s  += __shfl_down(s, off);
    ss += __shfl_down(ss, off);
  }
  const int wid = threadIdx.x >> 6;
  if ((threadIdx.x & 63) == 0) { wS[wid] = s; wSS[wid] = ss; }
  __syncthreads();
  if (threadIdx.x == 0) {
    const float S  = wS[0]  + wS[1]  + wS[2]  + wS[3];
    const float SS = wSS[0] + wSS[1] + wSS[2] + wSS[3];
    partials[blockIdx.x] = make_float2(S, SS);
  }
}

// ---------------------------------------------------------------------------
// Kernel 2: deterministic finalize.
//   per unit: std = sqrt((SS - S*S/CNT) / (CNT-1))   (ddof=1 over all N*D)
//   per batch: sigma = max(std_dir0, std_dir1); out = mean over batches.
// ---------------------------------------------------------------------------
__global__ __launch_bounds__(256) void finalize_kernel(
    const float2* __restrict__ partials, float* __restrict__ out) {
  __shared__ float2 sh[TOTAL_BLOCKS];
  __shared__ float sig[NUNITS];

  sh[threadIdx.x] = partials[threadIdx.x];
  __syncthreads();

  if (threadIdx.x < NUNITS) {
    float S = 0.f, SS = 0.f;
    #pragma unroll
    for (int i = 0; i < BLOCKS_PER_UNIT; ++i) {
      S  += sh[threadIdx.x * BLOCKS_PER_UNIT + i].x;
      SS += sh[threadIdx.x * BLOCKS_PER_UNIT + i].y;
    }
    const float var = (SS - S * S / CNT) / (CNT - 1.0f);
    sig[threadIdx.x] = sqrtf(fmaxf(var, 0.0f));
  }
  __syncthreads();

  if (threadIdx.x == 0) {
    float acc = 0.f;
    #pragma unroll
    for (int b = 0; b < 8; ++b) acc += fmaxf(sig[2 * b], sig[2 * b + 1]);
    out[0] = acc * 0.125f;
  }
}

// ---------------------------------------------------------------------------
extern "C" void kernel_launch(void* const* d_in, const int* in_sizes, int n_in,
                              void* d_out, int out_size, void* d_ws, size_t ws_size,
                              hipStream_t stream) {
  const float* x = (const float*)d_in[0];
  const float* y = (const float*)d_in[1];
  float* out = (float*)d_out;
  float2* partials = (float2*)d_ws;   // 256 * 8 B = 2 KB scratch

  hipLaunchKernelGGL(nn_partial_kernel, dim3(TOTAL_BLOCKS), dim3(BLK), 0, stream,
                     x, y, partials);
  hipLaunchKernelGGL(finalize_kernel, dim3(1), dim3(256), 0, stream,
                     partials, out);
}

// Round 2
// 80.028 us; speedup vs baseline: 1.3631x; 1.3631x over previous
//
#include <hip/hip_runtime.h>
#include <math.h>

#define NPTS 4096
#define BLK 256
#define NUNITS 16                      // 8 batches * 2 directions
#define T_CHUNKS 4
#define CSZ (NPTS / T_CHUNKS)          // 1024 targets per chunk
#define QBLKS (NPTS / BLK)             // 16 query-blocks per unit
#define GRID1 (NUNITS * QBLKS * T_CHUNKS)   // 1024 blocks
#define GRID2 (NUNITS * QBLKS)              // 256 blocks
#define CNT 12288.0f                   // N*D elements per std
#define KEY_WORDS (NUNITS * T_CHUNKS * NPTS) // 262144 u32 = 1 MB

// ---------------------------------------------------------------------------
// Kernel 1 (two-phase path): per (unit, query, target-chunk) packed argmin key.
// key = (d2_bits & 0xFFFFF000) | global_j   (d2 >= 0 so uint order == float
// order; low 12 bits carry the index, giving first-index tie-break on min).
// ---------------------------------------------------------------------------
__global__ __launch_bounds__(BLK) void nn_keys_kernel(
    const float* __restrict__ x, const float* __restrict__ y,
    unsigned* __restrict__ keys) {
  __shared__ float4 tgt[CSZ];          // 16 KB

  const int bid   = blockIdx.x;
  const int unit  = bid >> 6;          // 16 qblk * 4 chunks = 64 blocks/unit
  const int qblk  = (bid >> 2) & 15;
  const int chunk = bid & 3;
  const int b   = unit >> 1;
  const int dir = unit & 1;
  const float* __restrict__ A  = (dir ? y : x) + (size_t)b * NPTS * 3;
  const float* __restrict__ Bc = (dir ? x : y) + (size_t)b * NPTS * 3
                                 + (size_t)chunk * CSZ * 3;

  // Stage this target chunk into LDS as float4 (one b128 broadcast per read).
  for (int i = threadIdx.x; i < CSZ; i += BLK) {
    tgt[i] = make_float4(Bc[3 * i], Bc[3 * i + 1], Bc[3 * i + 2], 0.f);
  }
  __syncthreads();

  const int q = qblk * BLK + (int)threadIdx.x;
  const float qx = A[3 * q], qy = A[3 * q + 1], qz = A[3 * q + 2];
  const unsigned jbase = (unsigned)(chunk * CSZ);

  unsigned bk0 = 0xFFFFFFFFu, bk1 = 0xFFFFFFFFu;
  unsigned bk2 = 0xFFFFFFFFu, bk3 = 0xFFFFFFFFu;
  #pragma unroll 2
  for (int j = 0; j < CSZ; j += 4) {
    const float4 t0 = tgt[j + 0];
    const float4 t1 = tgt[j + 1];
    const float4 t2 = tgt[j + 2];
    const float4 t3 = tgt[j + 3];
    {
      const float dx = qx - t0.x, dy = qy - t0.y, dz = qz - t0.z;
      const float d2 = fmaf(dx, dx, fmaf(dy, dy, dz * dz));
      const unsigned key = (__float_as_uint(d2) & 0xFFFFF000u) | (jbase + (unsigned)j);
      bk0 = bk0 < key ? bk0 : key;
    }
    {
      const float dx = qx - t1.x, dy = qy - t1.y, dz = qz - t1.z;
      const float d2 = fmaf(dx, dx, fmaf(dy, dy, dz * dz));
      const unsigned key = (__float_as_uint(d2) & 0xFFFFF000u) | (jbase + (unsigned)j + 1u);
      bk1 = bk1 < key ? bk1 : key;
    }
    {
      const float dx = qx - t2.x, dy = qy - t2.y, dz = qz - t2.z;
      const float d2 = fmaf(dx, dx, fmaf(dy, dy, dz * dz));
      const unsigned key = (__float_as_uint(d2) & 0xFFFFF000u) | (jbase + (unsigned)j + 2u);
      bk2 = bk2 < key ? bk2 : key;
    }
    {
      const float dx = qx - t3.x, dy = qy - t3.y, dz = qz - t3.z;
      const float d2 = fmaf(dx, dx, fmaf(dy, dy, dz * dz));
      const unsigned key = (__float_as_uint(d2) & 0xFFFFF000u) | (jbase + (unsigned)j + 3u);
      bk3 = bk3 < key ? bk3 : key;
    }
  }
  const unsigned bk01 = bk0 < bk1 ? bk0 : bk1;
  const unsigned bk23 = bk2 < bk3 ? bk2 : bk3;
  const unsigned bk = bk01 < bk23 ? bk01 : bk23;

  keys[((unsigned)(unit * T_CHUNKS + chunk) << 12) | (unsigned)q] = bk;
}

// ---------------------------------------------------------------------------
// Kernel 2: combine chunk keys per query, gather winning target, exact
// residual, deterministic per-block (sum, sumsq) partial.
// ---------------------------------------------------------------------------
__global__ __launch_bounds__(BLK) void combine_kernel(
    const float* __restrict__ x, const float* __restrict__ y,
    const unsigned* __restrict__ keys, float2* __restrict__ partials) {
  __shared__ float wS[4], wSS[4];

  const int bid  = blockIdx.x;         // unit*16 + qblk
  const int unit = bid >> 4;
  const int b = unit >> 1, dir = unit & 1;
  const float* __restrict__ A  = (dir ? y : x) + (size_t)b * NPTS * 3;
  const float* __restrict__ Bc = (dir ? x : y) + (size_t)b * NPTS * 3;
  const int q = ((bid & 15) << 8) + (int)threadIdx.x;

  unsigned bk = 0xFFFFFFFFu;
  #pragma unroll
  for (int c = 0; c < T_CHUNKS; ++c) {
    const unsigned k = keys[((unsigned)(unit * T_CHUNKS + c) << 12) | (unsigned)q];
    bk = bk < k ? bk : k;
  }
  const int j = (int)(bk & 4095u);

  const float rx = A[3 * q]     - Bc[3 * j];
  const float ry = A[3 * q + 1] - Bc[3 * j + 1];
  const float rz = A[3 * q + 2] - Bc[3 * j + 2];
  float s  = rx + ry + rz;
  float ss = fmaf(rx, rx, fmaf(ry, ry, rz * rz));

  #pragma unroll
  for (int off = 32; off > 0; off >>= 1) {
    s  += __shfl_down(s, off);
    ss += __shfl_down(ss, off);
  }
  const int wid = threadIdx.x >> 6;
  if ((threadIdx.x & 63) == 0) { wS[wid] = s; wSS[wid] = ss; }
  __syncthreads();
  if (threadIdx.x == 0) {
    partials[bid] = make_float2(wS[0] + wS[1] + wS[2] + wS[3],
                                wSS[0] + wSS[1] + wSS[2] + wSS[3]);
  }
}

// ---------------------------------------------------------------------------
// Kernel 3: deterministic finalize (unchanged).
// ---------------------------------------------------------------------------
__global__ __launch_bounds__(256) void finalize_kernel(
    const float2* __restrict__ partials, float* __restrict__ out) {
  __shared__ float2 sh[GRID2];
  __shared__ float sig[NUNITS];

  sh[threadIdx.x] = partials[threadIdx.x];
  __syncthreads();

  if (threadIdx.x < NUNITS) {
    float S = 0.f, SS = 0.f;
    #pragma unroll
    for (int i = 0; i < QBLKS; ++i) {
      S  += sh[threadIdx.x * QBLKS + i].x;
      SS += sh[threadIdx.x * QBLKS + i].y;
    }
    const float var = (SS - S * S / CNT) / (CNT - 1.0f);
    sig[threadIdx.x] = sqrtf(fmaxf(var, 0.0f));
  }
  __syncthreads();

  if (threadIdx.x == 0) {
    float acc = 0.f;
    #pragma unroll
    for (int b = 0; b < 8; ++b) acc += fmaxf(sig[2 * b], sig[2 * b + 1]);
    out[0] = acc * 0.125f;
  }
}

// ---------------------------------------------------------------------------
// Fallback single-phase kernel (round-1, known-good) if ws is too small.
// ---------------------------------------------------------------------------
__global__ __launch_bounds__(BLK) void nn_partial_kernel(
    const float* __restrict__ x, const float* __restrict__ y,
    float2* __restrict__ partials) {
  __shared__ float tx[NPTS];
  __shared__ float ty[NPTS];
  __shared__ float tz[NPTS];
  __shared__ float wS[4], wSS[4];

  const int unit = blockIdx.x >> 4;
  const int blk  = blockIdx.x & 15;
  const int b    = unit >> 1;
  const int dir  = unit & 1;
  const float* __restrict__ Aptr = (dir == 0 ? x : y) + (size_t)b * NPTS * 3;
  const float* __restrict__ Bptr = (dir == 0 ? y : x) + (size_t)b * NPTS * 3;

  for (int i = threadIdx.x; i < NPTS; i += BLK) {
    tx[i] = Bptr[3 * i + 0];
    ty[i] = Bptr[3 * i + 1];
    tz[i] = Bptr[3 * i + 2];
  }
  __syncthreads();

  const int q = blk * BLK + (int)threadIdx.x;
  const float qx = Aptr[3 * q + 0];
  const float qy = Aptr[3 * q + 1];
  const float qz = Aptr[3 * q + 2];

  float best = 3.4e38f;
  int bi = 0;
  #pragma unroll 8
  for (int j = 0; j < NPTS; ++j) {
    const float dx = qx - tx[j];
    const float dy = qy - ty[j];
    const float dz = qz - tz[j];
    const float d2 = fmaf(dx, dx, fmaf(dy, dy, dz * dz));
    if (d2 < best) { best = d2; bi = j; }
  }

  const float rx = qx - tx[bi];
  const float ry = qy - ty[bi];
  const float rz = qz - tz[bi];
  float s  = rx + ry + rz;
  float ss = fmaf(rx, rx, fmaf(ry, ry, rz * rz));

  #pragma unroll
  for (int off = 32; off > 0; off >>= 1) {
    s  += __shfl_down(s, off);
    ss += __shfl_down(ss, off);
  }
  const int wid = threadIdx.x >> 6;
  if ((threadIdx.x & 63) == 0) { wS[wid] = s; wSS[wid] = ss; }
  __syncthreads();
  if (threadIdx.x == 0) {
    partials[blockIdx.x] = make_float2(wS[0] + wS[1] + wS[2] + wS[3],
                                       wSS[0] + wSS[1] + wSS[2] + wSS[3]);
  }
}

// ---------------------------------------------------------------------------
extern "C" void kernel_launch(void* const* d_in, const int* in_sizes, int n_in,
                              void* d_out, int out_size, void* d_ws, size_t ws_size,
                              hipStream_t stream) {
  const float* x = (const float*)d_in[0];
  const float* y = (const float*)d_in[1];
  float* out = (float*)d_out;

  const size_t key_bytes = (size_t)KEY_WORDS * 4;           // 1 MB
  const size_t need = key_bytes + (size_t)GRID2 * sizeof(float2);

  if (ws_size >= need) {
    unsigned* keys = (unsigned*)d_ws;
    float2* partials = (float2*)((char*)d_ws + key_bytes);
    hipLaunchKernelGGL(nn_keys_kernel, dim3(GRID1), dim3(BLK), 0, stream, x, y, keys);
    hipLaunchKernelGGL(combine_kernel, dim3(GRID2), dim3(BLK), 0, stream,
                       x, y, keys, partials);
    hipLaunchKernelGGL(finalize_kernel, dim3(1), dim3(256), 0, stream, partials, out);
  } else {
    float2* partials = (float2*)d_ws;                       // 2 KB
    hipLaunchKernelGGL(nn_partial_kernel, dim3(GRID2), dim3(BLK), 0, stream,
                       x, y, partials);
    hipLaunchKernelGGL(finalize_kernel, dim3(1), dim3(256), 0, stream, partials, out);
  }
}

// Round 3
// 36.063 us; speedup vs baseline: 3.0249x; 2.2191x over previous
//
#include <hip/hip_runtime.h>
#include <math.h>

#define NPTS 4096
#define BLK 256
#define NUNITS 16                      // 8 batches * 2 directions
#define T_CHUNKS 4
#define CSZ 1024                       // targets per chunk
#define QGRPS 8
#define QG 512                         // queries per block
#define GRID1 (NUNITS * QGRPS * T_CHUNKS)   // 512 blocks
#define QBLKS (NPTS / BLK)             // 16
#define GRID2 (NUNITS * QBLKS)         // 256 blocks
#define CNT 12288.0f
#define KEY_WORDS (NUNITS * T_CHUNKS * NPTS) // 262144 u32 = 1 MB

typedef _Float16 half8 __attribute__((ext_vector_type(8)));
typedef float f32x16 __attribute__((ext_vector_type(16)));

__device__ __forceinline__ unsigned umin2(unsigned a, unsigned b) { return a < b ? a : b; }

// In-lane argmin over one MFMA tile result: pack (d2 top-20 bits | t-index
// low bits) and min-reduce the 16 regs. Row/index bit fields are disjoint:
// row_r = (r&3)+8*(r>>2) uses bits {0,1,3,4}; the per-lane 4*(lane>>5) bit 2
// is OR-ed by the caller AFTER the t-loop (constant per lane, order-safe).
__device__ __forceinline__ unsigned tilemin(const f32x16 d, unsigned ob) {
  unsigned k[16];
  #pragma unroll
  for (int r = 0; r < 16; ++r) {
    const unsigned row = (unsigned)((r & 3) + 8 * (r >> 2));
    k[r] = (__float_as_uint(d[r]) & 0xFFFFF000u) | (ob + row);
  }
  const unsigned m = umin2(umin2(umin2(k[0], k[1]), umin2(k[2], k[3])),
                           umin2(umin2(k[4], k[5]), umin2(k[6], k[7])));
  const unsigned n = umin2(umin2(umin2(k[8], k[9]), umin2(k[10], k[11])),
                           umin2(umin2(k[12], k[13]), umin2(k[14], k[15])));
  return umin2(m, n);
}

// ---------------------------------------------------------------------------
// Kernel 1: fused fp16-split pack + MFMA distance + in-register argmin keys.
// d2[t][q] = b2 + a2 - 2 a.b via ONE 32x32x16 f16 MFMA per tile:
//  k0-2 : A=bh_c        B=-2*ah_c
//  k3-5 : A=bl_c        B=-2*ah_c
//  k6-8 : A=bh_c        B=-2*al_c
//  k9,10: A=b2h,b2l     B=1,1
//  k11,12:A=1,1         B=a2h,a2l
//  k13-15: 0
// (al*bl dropped: |err| ~1e-5 absolute — only affects near-tie argmin picks.)
// ---------------------------------------------------------------------------
__global__ __launch_bounds__(BLK) void mfma_keys_kernel(
    const float* __restrict__ x, const float* __restrict__ y,
    unsigned* __restrict__ keys) {
  __shared__ half8 Ap[CSZ * 2];   // 32 KB target pack, row t = 2 half8 (16 k-slots)
  __shared__ half8 Bp[QG * 2];    // 16 KB query pack

  const int bid   = blockIdx.x;
  const int unit  = bid >> 5;        // 8 qgrps * 4 chunks = 32 blocks/unit
  const int qgrp  = (bid >> 2) & 7;
  const int chunk = bid & 3;
  const int b = unit >> 1, dir = unit & 1;
  const float* __restrict__ Q = (dir ? y : x) + (size_t)b * NPTS * 3;  // queries
  const float* __restrict__ T = (dir ? x : y) + (size_t)b * NPTS * 3;  // targets

  const int tid = threadIdx.x;
  const _Float16 one  = (_Float16)1.0f;
  const _Float16 zero = (_Float16)0.0f;
  const _Float16 n2   = (_Float16)(-2.0f);

  // ---- pack targets (A rows) ----
  for (int k = 0; k < 4; ++k) {
    const int i  = tid + k * BLK;          // 0..1023
    const int tg = chunk * CSZ + i;
    const float bx = T[3 * tg], by = T[3 * tg + 1], bz = T[3 * tg + 2];
    const float b2 = fmaf(bx, bx, fmaf(by, by, bz * bz));
    const _Float16 bh0 = (_Float16)bx, bh1 = (_Float16)by, bh2 = (_Float16)bz;
    const _Float16 bl0 = (_Float16)(bx - (float)bh0);
    const _Float16 bl1 = (_Float16)(by - (float)bh1);
    const _Float16 bl2 = (_Float16)(bz - (float)bh2);
    const _Float16 s2h = (_Float16)b2;
    const _Float16 s2l = (_Float16)(b2 - (float)s2h);
    half8 lo, hi;
    lo[0] = bh0; lo[1] = bh1; lo[2] = bh2; lo[3] = bl0;
    lo[4] = bl1; lo[5] = bl2; lo[6] = bh0; lo[7] = bh1;
    hi[0] = bh2; hi[1] = s2h; hi[2] = s2l; hi[3] = one;
    hi[4] = one; hi[5] = zero; hi[6] = zero; hi[7] = zero;
    Ap[i * 2]     = lo;
    Ap[i * 2 + 1] = hi;
  }
  // ---- pack queries (B cols) ----
  for (int k = 0; k < 2; ++k) {
    const int i  = tid + k * BLK;          // 0..511
    const int qg = qgrp * QG + i;
    const float ax = Q[3 * qg], ay = Q[3 * qg + 1], az = Q[3 * qg + 2];
    const float a2 = fmaf(ax, ax, fmaf(ay, ay, az * az));
    const _Float16 ah0 = (_Float16)ax, ah1 = (_Float16)ay, ah2 = (_Float16)az;
    const _Float16 al0 = (_Float16)(ax - (float)ah0);
    const _Float16 al1 = (_Float16)(ay - (float)ah1);
    const _Float16 al2 = (_Float16)(az - (float)ah2);
    const _Float16 a2h = (_Float16)a2;
    const _Float16 a2l = (_Float16)(a2 - (float)a2h);
    half8 lo, hi;
    lo[0] = n2 * ah0; lo[1] = n2 * ah1; lo[2] = n2 * ah2; lo[3] = n2 * ah0;
    lo[4] = n2 * ah1; lo[5] = n2 * ah2; lo[6] = n2 * al0; lo[7] = n2 * al1;
    hi[0] = n2 * al2; hi[1] = one; hi[2] = one; hi[3] = a2h;
    hi[4] = a2l; hi[5] = zero; hi[6] = zero; hi[7] = zero;
    Bp[i * 2]     = lo;
    Bp[i * 2 + 1] = hi;
  }
  __syncthreads();

  const int lane = tid & 63;
  const int w    = tid >> 6;           // wave 0..3 -> 128 queries each
  const int ln   = lane & 31;
  const int hi5  = lane >> 5;
  const unsigned vhib = (unsigned)(hi5 << 2);   // row bit 2 (deferred OR)

  // B fragments: lane holds B[k=8*hi5+e][q = qbase + ln]
  const half8 bf0 = Bp[(w * 128 +   0 + ln) * 2 + hi5];
  const half8 bf1 = Bp[(w * 128 +  32 + ln) * 2 + hi5];
  const half8 bf2 = Bp[(w * 128 +  64 + ln) * 2 + hi5];
  const half8 bf3 = Bp[(w * 128 +  96 + ln) * 2 + hi5];

  f32x16 Z;
  #pragma unroll
  for (int r = 0; r < 16; ++r) Z[r] = 0.0f;

  unsigned kacc0 = 0xFFFFFFFFu, kacc1 = 0xFFFFFFFFu;
  unsigned kacc2 = 0xFFFFFFFFu, kacc3 = 0xFFFFFFFFu;
  const unsigned ob0 = (unsigned)(chunk * CSZ);

  #pragma unroll 2
  for (int t = 0; t < CSZ / 32; ++t) {
    const half8 af = Ap[(t * 32 + ln) * 2 + hi5];  // A[t0+ln][k=8*hi5+e]
    const f32x16 d0 = __builtin_amdgcn_mfma_f32_32x32x16_f16(af, bf0, Z, 0, 0, 0);
    const f32x16 d1 = __builtin_amdgcn_mfma_f32_32x32x16_f16(af, bf1, Z, 0, 0, 0);
    const f32x16 d2 = __builtin_amdgcn_mfma_f32_32x32x16_f16(af, bf2, Z, 0, 0, 0);
    const f32x16 d3 = __builtin_amdgcn_mfma_f32_32x32x16_f16(af, bf3, Z, 0, 0, 0);
    const unsigned ob = ob0 + (unsigned)(t * 32);
    kacc0 = umin2(kacc0, tilemin(d0, ob));
    kacc1 = umin2(kacc1, tilemin(d1, ob));
    kacc2 = umin2(kacc2, tilemin(d2, ob));
    kacc3 = umin2(kacc3, tilemin(d3, ob));
  }

  kacc0 |= vhib; kacc1 |= vhib; kacc2 |= vhib; kacc3 |= vhib;
  kacc0 = umin2(kacc0, (unsigned)__shfl_xor((int)kacc0, 32));
  kacc1 = umin2(kacc1, (unsigned)__shfl_xor((int)kacc1, 32));
  kacc2 = umin2(kacc2, (unsigned)__shfl_xor((int)kacc2, 32));
  kacc3 = umin2(kacc3, (unsigned)__shfl_xor((int)kacc3, 32));

  if (lane < 32) {
    const unsigned base = ((unsigned)(unit * T_CHUNKS + chunk) << 12);
    const unsigned qb   = (unsigned)(qgrp * QG + w * 128);
    keys[base | (qb +  0 + (unsigned)ln)] = kacc0;
    keys[base | (qb + 32 + (unsigned)ln)] = kacc1;
    keys[base | (qb + 64 + (unsigned)ln)] = kacc2;
    keys[base | (qb + 96 + (unsigned)ln)] = kacc3;
  }
}

// ---------------------------------------------------------------------------
// Kernel 2: combine chunk keys per query, gather winning target, exact fp32
// residual, deterministic per-block (sum, sumsq) partial.
// ---------------------------------------------------------------------------
__global__ __launch_bounds__(BLK) void combine_kernel(
    const float* __restrict__ x, const float* __restrict__ y,
    const unsigned* __restrict__ keys, float2* __restrict__ partials) {
  __shared__ float wS[4], wSS[4];

  const int bid  = blockIdx.x;         // unit*16 + qblk
  const int unit = bid >> 4;
  const int b = unit >> 1, dir = unit & 1;
  const float* __restrict__ A  = (dir ? y : x) + (size_t)b * NPTS * 3;
  const float* __restrict__ Bc = (dir ? x : y) + (size_t)b * NPTS * 3;
  const int q = ((bid & 15) << 8) + (int)threadIdx.x;

  unsigned bk = 0xFFFFFFFFu;
  #pragma unroll
  for (int c = 0; c < T_CHUNKS; ++c) {
    const unsigned k = keys[((unsigned)(unit * T_CHUNKS + c) << 12) | (unsigned)q];
    bk = bk < k ? bk : k;
  }
  const int j = (int)(bk & 4095u);

  const float rx = A[3 * q]     - Bc[3 * j];
  const float ry = A[3 * q + 1] - Bc[3 * j + 1];
  const float rz = A[3 * q + 2] - Bc[3 * j + 2];
  float s  = rx + ry + rz;
  float ss = fmaf(rx, rx, fmaf(ry, ry, rz * rz));

  #pragma unroll
  for (int off = 32; off > 0; off >>= 1) {
    s  += __shfl_down(s, off);
    ss += __shfl_down(ss, off);
  }
  const int wid = threadIdx.x >> 6;
  if ((threadIdx.x & 63) == 0) { wS[wid] = s; wSS[wid] = ss; }
  __syncthreads();
  if (threadIdx.x == 0) {
    partials[bid] = make_float2(wS[0] + wS[1] + wS[2] + wS[3],
                                wSS[0] + wSS[1] + wSS[2] + wSS[3]);
  }
}

// ---------------------------------------------------------------------------
// Kernel 3: deterministic finalize.
// ---------------------------------------------------------------------------
__global__ __launch_bounds__(256) void finalize_kernel(
    const float2* __restrict__ partials, float* __restrict__ out) {
  __shared__ float2 sh[GRID2];
  __shared__ float sig[NUNITS];

  sh[threadIdx.x] = partials[threadIdx.x];
  __syncthreads();

  if (threadIdx.x < NUNITS) {
    float S = 0.f, SS = 0.f;
    #pragma unroll
    for (int i = 0; i < QBLKS; ++i) {
      S  += sh[threadIdx.x * QBLKS + i].x;
      SS += sh[threadIdx.x * QBLKS + i].y;
    }
    const float var = (SS - S * S / CNT) / (CNT - 1.0f);
    sig[threadIdx.x] = sqrtf(fmaxf(var, 0.0f));
  }
  __syncthreads();

  if (threadIdx.x == 0) {
    float acc = 0.f;
    #pragma unroll
    for (int b = 0; b < 8; ++b) acc += fmaxf(sig[2 * b], sig[2 * b + 1]);
    out[0] = acc * 0.125f;
  }
}

// ---------------------------------------------------------------------------
extern "C" void kernel_launch(void* const* d_in, const int* in_sizes, int n_in,
                              void* d_out, int out_size, void* d_ws, size_t ws_size,
                              hipStream_t stream) {
  const float* x = (const float*)d_in[0];
  const float* y = (const float*)d_in[1];
  float* out = (float*)d_out;

  const size_t key_bytes = (size_t)KEY_WORDS * 4;           // 1 MB (fits: proven R2)
  unsigned* keys = (unsigned*)d_ws;
  float2* partials = (float2*)((char*)d_ws + key_bytes);

  hipLaunchKernelGGL(mfma_keys_kernel, dim3(GRID1), dim3(BLK), 0, stream, x, y, keys);
  hipLaunchKernelGGL(combine_kernel, dim3(GRID2), dim3(BLK), 0, stream,
                     x, y, keys, partials);
  hipLaunchKernelGGL(finalize_kernel, dim3(1), dim3(256), 0, stream, partials, out);
}